// Round 1
// baseline (1274.778 us; speedup 1.0000x reference)
//
#include <hip/hip_runtime.h>

#define E_EDGES   800000
#define HIDN      128
#define EDIMN     32
#define T_EDGES   128
#define NTILES    (E_EDGES / T_EDGES)   // 6250
#define MW        32                    // edge rows per wave
#define GRID_MAIN 256

typedef __attribute__((ext_vector_type(8))) short bf16x8;
typedef __attribute__((ext_vector_type(4))) float f32x4;

static __device__ __forceinline__ unsigned short f2bf(float f) {
  unsigned int u = __float_as_uint(f);
  u += 0x7fffu + ((u >> 16) & 1u);
  return (unsigned short)(u >> 16);
}

// swizzled element index inside a row-major [rows][128] bf16 buffer.
// 16B-slot XOR swizzle: byte ^= (row&7)<<4  ->  elem ^= (row&7)<<3
static __device__ __forceinline__ int swz(int row, int kElem) {
  return row * HIDN + (kElem ^ ((row & 7) << 3));
}

// ---- detect whether edge_index arrived as int64 (odd 32-bit words all zero)
__global__ void k_detect(const int* __restrict__ ei, int* __restrict__ flag) {
  __shared__ int nz;
  if (threadIdx.x == 0) nz = 0;
  __syncthreads();
  if (ei[2 * threadIdx.x + 1] != 0) atomicAdd(&nz, 1);
  __syncthreads();
  if (threadIdx.x == 0) flag[0] = (nz == 0) ? 1 : 0;   // 1 => int64
}

// ---- normalize edge_index to packed int32 [src(0..E) | dst(E..2E)]
__global__ void k_norm(const int* __restrict__ ei, const int* __restrict__ flag,
                       int* __restrict__ idx) {
  const int stride = gridDim.x * blockDim.x;
  const int w = flag[0];
  for (int i = blockIdx.x * blockDim.x + threadIdx.x; i < 2 * E_EDGES; i += stride)
    idx[i] = w ? ei[2 * i] : ei[i];
}

// K=128 GEMM step: acc[2][8] = S[32x128] @ W (W stored transposed+swizzled in LDS)
#define MM128(WTp)                                                                        \
  {                                                                                       \
    for (int mb = 0; mb < 2; ++mb)                                                        \
      for (int cb = 0; cb < 8; ++cb) acc[mb][cb] = (f32x4){0.f, 0.f, 0.f, 0.f};           \
    for (int ks = 0; ks < 4; ++ks) {                                                      \
      bf16x8 a0 = *reinterpret_cast<const bf16x8*>(&S[swz(c16, ks * 32 + q * 8)]);        \
      bf16x8 a1 = *reinterpret_cast<const bf16x8*>(&S[swz(16 + c16, ks * 32 + q * 8)]);   \
      for (int cb = 0; cb < 8; ++cb) {                                                    \
        bf16x8 b = *reinterpret_cast<const bf16x8*>(&(WTp)[swz(cb * 16 + c16, ks * 32 + q * 8)]); \
        acc[0][cb] = __builtin_amdgcn_mfma_f32_16x16x32_bf16(a0, b, acc[0][cb], 0, 0, 0); \
        acc[1][cb] = __builtin_amdgcn_mfma_f32_16x16x32_bf16(a1, b, acc[1][cb], 0, 0, 0); \
      }                                                                                   \
    }                                                                                     \
  }

__launch_bounds__(256, 1)
__global__ void k_conv(const float* __restrict__ x, const float* __restrict__ ea,
                       const int* __restrict__ gidx, const int* __restrict__ sidx,
                       const float* __restrict__ We1, const float* __restrict__ be1,
                       const float* __restrict__ We2, const float* __restrict__ be2,
                       const float* __restrict__ Wm1, const float* __restrict__ bm1,
                       const float* __restrict__ Wm2, const float* __restrict__ bm2,
                       const float* __restrict__ alphap, int dir,
                       float* __restrict__ out) {
  __shared__ unsigned short wt[3][HIDN * HIDN];   // We2,Wm1,Wm2 transposed [n][k], 96KB
  __shared__ unsigned short st[4][MW * HIDN];     // per-wave staging, 32KB

  const int tid = threadIdx.x;
  const int wv  = tid >> 6;
  const int ln  = tid & 63;
  const int q   = ln >> 4;
  const int c16 = ln & 15;

  {  // stage weights into LDS (coalesced read W[k][n], write transposed+swizzled bf16)
    const float* Ws[3] = {We2, Wm1, Wm2};
    for (int m = 0; m < 3; ++m) {
      const float* W = Ws[m];
      for (int p = tid; p < HIDN * HIDN; p += 256) {
        int k = p >> 7, n = p & (HIDN - 1);
        wt[m][swz(n, k)] = f2bf(W[p]);
      }
    }
  }

  // We1^T B-fragments in registers (K=32: single k-step)
  bf16x8 fw1[8];
  for (int cb = 0; cb < 8; ++cb)
    for (int j = 0; j < 8; ++j)
      fw1[cb][j] = (short)f2bf(We1[(q * 8 + j) * HIDN + cb * 16 + c16]);

  float vb1[8], vb2[8], vm1[8], vm2[8];
  for (int cb = 0; cb < 8; ++cb) {
    int c = cb * 16 + c16;
    vb1[cb] = be1[c]; vb2[cb] = be2[c]; vm1[cb] = bm1[c]; vm2[cb] = bm2[c];
  }

  const float a     = 1.f / (1.f + expf(-alphap[0]));
  const float scale = dir ? (1.f - a) : a;

  __syncthreads();

  unsigned short* S = st[wv];

  for (int t = blockIdx.x; t < NTILES; t += gridDim.x) {
    const int e0 = t * T_EDGES + wv * MW;
    f32x4 acc[2][8];

    // ---- stage 1: relu(ea @ We1 + be1)  (A streamed from global)
    for (int mb = 0; mb < 2; ++mb) {
      const float* ap = &ea[(size_t)(e0 + mb * 16 + c16) * EDIMN + q * 8];
      float4 v0 = *reinterpret_cast<const float4*>(ap);
      float4 v1 = *reinterpret_cast<const float4*>(ap + 4);
      bf16x8 afrag;
      afrag[0] = (short)f2bf(v0.x); afrag[1] = (short)f2bf(v0.y);
      afrag[2] = (short)f2bf(v0.z); afrag[3] = (short)f2bf(v0.w);
      afrag[4] = (short)f2bf(v1.x); afrag[5] = (short)f2bf(v1.y);
      afrag[6] = (short)f2bf(v1.z); afrag[7] = (short)f2bf(v1.w);
      for (int cb = 0; cb < 8; ++cb) {
        f32x4 z = {0.f, 0.f, 0.f, 0.f};
        acc[mb][cb] = __builtin_amdgcn_mfma_f32_16x16x32_bf16(afrag, fw1[cb], z, 0, 0, 0);
      }
    }
    for (int mb = 0; mb < 2; ++mb)
      for (int j = 0; j < 4; ++j) {
        int r = mb * 16 + q * 4 + j;
        for (int cb = 0; cb < 8; ++cb) {
          float v = acc[mb][cb][j] + vb1[cb];
          v = v > 0.f ? v : 0.f;
          S[swz(r, cb * 16 + c16)] = f2bf(v);
        }
      }

    // ---- stage 2: e = S @ We2 + be2, then + x[gidx]
    MM128(wt[0]);
    for (int mb = 0; mb < 2; ++mb)
      for (int j = 0; j < 4; ++j) {
        int r = mb * 16 + q * 4 + j;
        int g = gidx[e0 + r];
        const float* xp = &x[(size_t)g * HIDN + c16];
        for (int cb = 0; cb < 8; ++cb) {
          float v = acc[mb][cb][j] + vb2[cb] + xp[cb * 16];
          S[swz(r, cb * 16 + c16)] = f2bf(v);
        }
      }

    // ---- stage 3: relu(S @ Wm1 + bm1)
    MM128(wt[1]);
    for (int mb = 0; mb < 2; ++mb)
      for (int j = 0; j < 4; ++j) {
        int r = mb * 16 + q * 4 + j;
        for (int cb = 0; cb < 8; ++cb) {
          float v = acc[mb][cb][j] + vm1[cb];
          v = v > 0.f ? v : 0.f;
          S[swz(r, cb * 16 + c16)] = f2bf(v);
        }
      }

    // ---- stage 4: m = S @ Wm2 + bm2; scaled atomic scatter to out[sidx]
    MM128(wt[2]);
    for (int mb = 0; mb < 2; ++mb)
      for (int j = 0; j < 4; ++j) {
        int r = mb * 16 + q * 4 + j;
        int d = sidx[e0 + r];
        float* op = &out[(size_t)d * HIDN + c16];
        for (int cb = 0; cb < 8; ++cb) {
          float v = scale * (acc[mb][cb][j] + vm2[cb]);
          unsafeAtomicAdd(op + cb * 16, v);
        }
      }
  }
}

extern "C" void kernel_launch(void* const* d_in, const int* in_sizes, int n_in,
                              void* d_out, int out_size, void* d_ws, size_t ws_size,
                              hipStream_t stream) {
  const float* x      = (const float*)d_in[0];
  const int*   ei     = (const int*)d_in[1];
  const float* ea     = (const float*)d_in[2];
  const float* alpha  = (const float*)d_in[3];
  const float* fWe1 = (const float*)d_in[4],  *fbe1 = (const float*)d_in[5];
  const float* fWe2 = (const float*)d_in[6],  *fbe2 = (const float*)d_in[7];
  const float* fWm1 = (const float*)d_in[8],  *fbm1 = (const float*)d_in[9];
  const float* fWm2 = (const float*)d_in[10], *fbm2 = (const float*)d_in[11];
  const float* bWe1 = (const float*)d_in[12], *bbe1 = (const float*)d_in[13];
  const float* bWe2 = (const float*)d_in[14], *bbe2 = (const float*)d_in[15];
  const float* bWm1 = (const float*)d_in[16], *bbm1 = (const float*)d_in[17];
  const float* bWm2 = (const float*)d_in[18], *bbm2 = (const float*)d_in[19];
  float* out = (float*)d_out;

  int* flag = (int*)d_ws;
  int* idx  = (int*)((char*)d_ws + 256);   // 2*E int32
  int* srcI = idx;
  int* dstI = idx + E_EDGES;

  hipMemsetAsync(d_out, 0, (size_t)out_size * sizeof(float), stream);
  k_detect<<<1, 256, 0, stream>>>(ei, flag);
  k_norm<<<2048, 256, 0, stream>>>(ei, flag, idx);

  // forward: gather x[src], scatter to dst, weight sigma(alpha)
  k_conv<<<GRID_MAIN, 256, 0, stream>>>(x, ea, srcI, dstI,
                                        fWe1, fbe1, fWe2, fbe2, fWm1, fbm1, fWm2, fbm2,
                                        alpha, 0, out);
  // backward: gather x[dst], scatter to src, weight 1-sigma(alpha)
  k_conv<<<GRID_MAIN, 256, 0, stream>>>(x, ea, dstI, srcI,
                                        bWe1, bbe1, bWe2, bbe2, bWm1, bbm1, bWm2, bbm2,
                                        alpha, 1, out);
}